// Round 15
// baseline (306.275 us; speedup 1.0000x reference)
//
#include <hip/hip_runtime.h>
#include <hip/hip_bf16.h>
#include <stdint.h>

typedef __bf16 bf16x8 __attribute__((ext_vector_type(8)));
typedef float f32x4 __attribute__((ext_vector_type(4)));
typedef float f32x16 __attribute__((ext_vector_type(16)));
typedef uint32_t u32x4 __attribute__((ext_vector_type(4)));
typedef unsigned short ushort_t;
typedef unsigned short ushort8v __attribute__((ext_vector_type(8)));

#define MFMA16 __builtin_amdgcn_mfma_f32_16x16x32_bf16
#define MFMA32 __builtin_amdgcn_mfma_f32_32x32x16_bf16

static constexpr int Bc = 2, Sc = 2048, Ec = 2048, Hc = 16;

__device__ __forceinline__ void gload16(const void* g, void* l) {
  __builtin_amdgcn_global_load_lds(
      (const __attribute__((address_space(1))) void*)g,
      (__attribute__((address_space(3))) void*)l, 16, 0, 0);
}

__device__ __forceinline__ ushort_t f2bf(float f) {
  uint32_t u = __float_as_uint(f);
  uint32_t r = (u + 0x7fffu + ((u >> 16) & 1u)) >> 16;
  return (ushort_t)r;
}
__device__ __forceinline__ float bf2f(ushort_t u) {
  return __uint_as_float((uint32_t)u << 16);
}
__device__ __forceinline__ uint32_t cvtpk(float a, float b) {
  uint32_t d;
  asm("v_cvt_pk_bf16_f32 %0, %1, %2" : "=v"(d) : "v"(a), "v"(b));
  return d;
}
// exchange: a[lanes 32..63] <-> b[lanes 0..31]
__device__ __forceinline__ void plswap(uint32_t& a, uint32_t& b) {
  asm("v_permlane32_swap_b32 %0, %1" : "+v"(a), "+v"(b));
}

// ---------------- fused casts: all 5 weight/x tensors in one launch ----------------
__global__ void cast_all(const float* __restrict__ x, const float* __restrict__ Wq,
                         const float* __restrict__ Wkvu, const float* __restrict__ Wout,
                         const float* __restrict__ Wkvd,
                         ushort_t* __restrict__ xb, ushort_t* __restrict__ wq,
                         ushort_t* __restrict__ wkvu, ushort_t* __restrict__ wout,
                         ushort_t* __restrict__ wkvd) {
  int i = blockIdx.x * 256 + threadIdx.x;
  const float* src;
  ushort_t* dst;
  int j;
  if (i < 2097152) { src = x; dst = xb; j = i; }
  else if (i < 3145728) { src = Wq; dst = wq; j = i - 2097152; }
  else if (i < 3538944) { src = Wkvu; dst = wkvu; j = i - 3145728; }
  else if (i < 4587520) { src = Wout; dst = wout; j = i - 3538944; }
  else {
    j = i - 4587520;                      // wkvd with row pad 576->640
    int row = j >> 9, col4 = j & 511;
    ushort4 o;
    if (row < 576) {
      float4 v = ((const float4*)Wkvd)[row * 512 + col4];
      o.x = f2bf(v.x); o.y = f2bf(v.y); o.z = f2bf(v.z); o.w = f2bf(v.w);
    } else { o.x = 0; o.y = 0; o.z = 0; o.w = 0; }
    ((ushort4*)wkvd)[j] = o;
    return;
  }
  float4 v = ((const float4*)src)[j];
  ushort4 o;
  o.x = f2bf(v.x); o.y = f2bf(v.y); o.z = f2bf(v.z); o.w = f2bf(v.w);
  ((ushort4*)dst)[j] = o;
}

// ---------------- prep: mask rearrange (blocks 0..2047) + rope_fill (blocks 2048..2175) ----------------
// mask: ushort8 unit u = q*256 + kt*8 + kblk*4 + half*2 + rr
//   element j = mask[q][kt*64 + kblk*32 + 4*half + (j&3) + 8*(2*rr+(j>>2))] / ln2
__global__ void prep_kernel(const float* __restrict__ mask, ushort_t* __restrict__ m4,
                            const ushort_t* __restrict__ comp, char* __restrict__ kbuf) {
  const float INVLN2 = 1.4426950408889634f;
  int gb = blockIdx.x;
  if (gb < 2048) {
    int i = gb * 256 + threadIdx.x;   // 524288 units
    int rr = i & 1, half = (i >> 1) & 1, kblk = (i >> 2) & 1, kt = (i >> 3) & 31, q = i >> 8;
    const float* src = mask + (size_t)q * 2048 + kt * 64 + kblk * 32 + half * 4 + rr * 16;
    float4 a = *(const float4*)src;         // j=0..3
    float4 c = *(const float4*)(src + 8);   // j=4..7
    ushort8v o;
    o[0] = f2bf(a.x * INVLN2); o[1] = f2bf(a.y * INVLN2);
    o[2] = f2bf(a.z * INVLN2); o[3] = f2bf(a.w * INVLN2);
    o[4] = f2bf(c.x * INVLN2); o[5] = f2bf(c.y * INVLN2);
    o[6] = f2bf(c.z * INVLN2); o[7] = f2bf(c.w * INVLN2);
    ((ushort8v*)m4)[i] = o;
  } else {
    int i = (gb - 2048) * 256 + threadIdx.x;  // B*S*8 = 32768 16-byte blocks
    int blk = i & 7;
    int m = i >> 3;
    int s = m & 2047, b = m >> 11;
    uint4 v = *(const uint4*)&comp[(size_t)m * 640 + 512 + blk * 8];
    int off = (blk * 16) ^ ((s & 7) << 4);
#pragma unroll
    for (int h = 0; h < Hc; h++) {
      *(uint4*)(kbuf + ((size_t)(b * Hc + h) * Sc + s) * 256 + off) = v;
    }
  }
}

// ---------------- GEMM 128x128, BK=64 (round-9 structure) — used for kv-down + kv-up ----------------
template<int MODE>
__global__ __launch_bounds__(256, 2)
void gemm_bt(const ushort_t* __restrict__ A, int lda,
             const ushort_t* __restrict__ Bm, int ldb,
             void* __restrict__ Cout, int ldc,
             int M, int N, int K,
             char* __restrict__ vtb, char* __restrict__ kbuf)
{
  __shared__ __align__(16) ushort_t sA[2][128 * 32];
  __shared__ __align__(16) ushort_t sB[2][128 * 32];
  int tid = threadIdx.x;
  int nTn = N >> 7;
  int bid = blockIdx.x;
  int chunk = gridDim.x >> 3;                       // grids are %8==0 -> bijective
  bid = (bid & 7) * chunk + (bid >> 3);             // XCD-chunked swizzle
  int tm = bid / nTn, tn = bid - tm * nTn;
  int wave = tid >> 6, lane = tid & 63;
  int wm = (wave >> 1) << 6, wn = (wave & 1) << 6;
  int l16 = lane & 15, g16 = lane >> 4;
  f32x4 acc[4][4] = {};
  int srow = tid >> 2, scol = (tid & 3) << 3;
  const ushort_t* Ag = A + (size_t)(tm * 128 + srow) * lda + scol;
  const ushort_t* Bg = Bm + (size_t)(tn * 128 + srow) * ldb + scol;
  ushort_t* sA0 = &sA[0][srow * 32 + scol];
  ushort_t* sA1 = &sA[1][srow * 32 + scol];
  ushort_t* sB0 = &sB[0][srow * 32 + scol];
  ushort_t* sB1 = &sB[1][srow * 32 + scol];
  for (int kt = 0; kt < K; kt += 64) {
    gload16(Ag, sA0);
    gload16(Ag + (size_t)64 * lda, sA0 + 64 * 32);
    gload16(Ag + 32, sA1);
    gload16(Ag + (size_t)64 * lda + 32, sA1 + 64 * 32);
    gload16(Bg, sB0);
    gload16(Bg + (size_t)64 * ldb, sB0 + 64 * 32);
    gload16(Bg + 32, sB1);
    gload16(Bg + (size_t)64 * ldb + 32, sB1 + 64 * 32);
    Ag += 64; Bg += 64;
    __syncthreads();
#pragma unroll
    for (int h2 = 0; h2 < 2; h2++) {
      bf16x8 af[4], bfr[4];
#pragma unroll
      for (int i = 0; i < 4; i++) af[i] = *(const bf16x8*)&sA[h2][(wm + i * 16 + l16) * 32 + g16 * 8];
#pragma unroll
      for (int i = 0; i < 4; i++) bfr[i] = *(const bf16x8*)&sB[h2][(wn + i * 16 + l16) * 32 + g16 * 8];
#pragma unroll
      for (int i = 0; i < 4; i++)
#pragma unroll
        for (int j = 0; j < 4; j++)
          acc[i][j] = MFMA16(af[i], bfr[j], acc[i][j], 0, 0, 0);
    }
    __syncthreads();
  }
  // epilogue: C/D layout col=lane&15, row=(lane>>4)*4+r
#pragma unroll
  for (int i = 0; i < 4; i++) {
#pragma unroll
    for (int j = 0; j < 4; j++) {
      int grow0 = tm * 128 + wm + i * 16 + g16 * 4;
      int gcol = tn * 128 + wn + j * 16 + l16;
      if constexpr (MODE == 0) {
#pragma unroll
        for (int r = 0; r < 4; r++)
          ((ushort_t*)Cout)[(size_t)(grow0 + r) * ldc + gcol] = f2bf(acc[i][j][r]);
      } else {
        int h = gcol / 192, jj = gcol - h * 192;
        int b = grow0 >> 11, s0 = grow0 & 2047;
        size_t bh = (size_t)(b * Hc + h);
        if (jj < 128) {
          // V^T, pre-swizzled; 4 consecutive s -> one 8B store (s0 %4==0, same 64-chunk)
          ushort4 pk;
          pk.x = f2bf(acc[i][j][0]); pk.y = f2bf(acc[i][j][1]);
          pk.z = f2bf(acc[i][j][2]); pk.w = f2bf(acc[i][j][3]);
          *(ushort4*)(vtb + bh * 524288 + (size_t)jj * 4096 + ((s0 >> 6) * 128) +
                      ((2 * (s0 & 63)) ^ ((jj & 7) << 4))) = pk;
        } else {
          int col = 64 + (jj - 128);                    // nope -> k dims 64..127
#pragma unroll
          for (int r = 0; r < 4; r++) {
            int s = s0 + r;
            *(ushort_t*)(kbuf + (bh * Sc + s) * 256 + ((2 * col) ^ ((s & 7) << 4))) = f2bf(acc[i][j][r]);
          }
        }
      }
    }
  }
}

// ---------------- GEMM 256x256, BK=64, deep-pipelined (m198/m201 structure) ----------------
// 512 thr = 8 waves (2M x 4N); LDS 128KB dbuf; 1 barrier per K-tile; prefetch issued
// right after the barrier so the next barrier's vmcnt(0) drains loads a full K-tile old.
// T2 swizzle c ^= ((row&7)<<4), applied on BOTH sides (rule #21): linear gload_lds dest
// + inverse-swizzled per-lane global source column + swizzled ds_read address.
template<int OUTF>   // 0 = bf16 store, 2 = f32 store
__global__ __launch_bounds__(512, 2)
void gemm256(const ushort_t* __restrict__ A, const ushort_t* __restrict__ Bm,
             void* __restrict__ Cout, int M, int N, int K)
{
  __shared__ __align__(16) ushort_t sA[2][256 * 64];
  __shared__ __align__(16) ushort_t sB[2][256 * 64];
  int tid = threadIdx.x;
  int nTn = N >> 8;
  int bid = blockIdx.x;
  int chunk = gridDim.x >> 3;                       // grid %8==0 -> bijective
  bid = (bid & 7) * chunk + (bid >> 3);             // XCD-chunked swizzle
  int tm = bid / nTn, tn = bid - tm * nTn;
  int wave = tid >> 6, lane = tid & 63;
  int wm = wave >> 2, wn = wave & 3;                // 2M x 4N wave grid
  int l16 = lane & 15, g16 = lane >> 4;
  f32x4 acc[8][4] = {};

  // staging: it in 0..3 -> row = it*64 + (tid>>3); 16B chunk; source col pre-swizzled
  int srow0 = tid >> 3;            // 0..63 ; row&7 == srow0&7 for all it
  int colsw = ((tid & 7) ^ (srow0 & 7)) * 8;        // element offset
  const ushort_t* Ag = A + (size_t)(tm * 256 + srow0) * K + colsw;
  const ushort_t* Bg = Bm + (size_t)(tn * 256 + srow0) * K + colsw;

  auto ISSUE = [&](int kk, int nb) {
#pragma unroll
    for (int it = 0; it < 4; it++) {
      gload16(Ag + (size_t)(it * 64) * K + kk, (char*)sA[nb] + it * 8192 + tid * 16);
      gload16(Bg + (size_t)(it * 64) * K + kk, (char*)sB[nb] + it * 8192 + tid * 16);
    }
  };

  ISSUE(0, 0);
  int Kt = K >> 6;
  int csw = (l16 & 7) << 4;
  for (int kt = 0; kt < Kt; kt++) {
    int buf = kt & 1;
    __syncthreads();               // drains vmcnt(0): this tile's loads (issued last iter)
    if (kt + 1 < Kt) ISSUE((kt + 1) * 64, buf ^ 1);
    const char* bA = (const char*)sA[buf];
    const char* bB = (const char*)sB[buf];
#pragma unroll
    for (int ks = 0; ks < 2; ks++) {
      int c = (ks * 64 + g16 * 16) ^ csw;
      bf16x8 bf[4];
#pragma unroll
      for (int j = 0; j < 4; j++)
        bf[j] = *(const bf16x8*)(bB + (wn * 64 + j * 16 + l16) * 128 + c);
#pragma unroll
      for (int mh = 0; mh < 2; mh++) {
        bf16x8 af[4];
#pragma unroll
        for (int i = 0; i < 4; i++)
          af[i] = *(const bf16x8*)(bA + (wm * 128 + mh * 64 + i * 16 + l16) * 128 + c);
        __builtin_amdgcn_s_setprio(1);
#pragma unroll
        for (int i = 0; i < 4; i++)
#pragma unroll
          for (int j = 0; j < 4; j++)
            acc[mh * 4 + i][j] = MFMA16(af[i], bf[j], acc[mh * 4 + i][j], 0, 0, 0);
        __builtin_amdgcn_s_setprio(0);
      }
    }
  }
  // epilogue: C/D layout col=lane&15, row=(lane>>4)*4+r
#pragma unroll
  for (int mi = 0; mi < 8; mi++) {
#pragma unroll
    for (int j = 0; j < 4; j++) {
      int grow0 = tm * 256 + wm * 128 + mi * 16 + g16 * 4;
      int gcol = tn * 256 + wn * 64 + j * 16 + l16;
#pragma unroll
      for (int r = 0; r < 4; r++) {
        if constexpr (OUTF == 0)
          ((ushort_t*)Cout)[(size_t)(grow0 + r) * N + gcol] = f2bf(acc[mi][j][r]);
        else
          ((float*)Cout)[(size_t)(grow0 + r) * N + gcol] = acc[mi][j][r];
      }
    }
  }
}

// ---------------- flash attention, 32x32 MFMA + swapped QK^T + in-register P (round-6, best) ----------------
__global__ __launch_bounds__(128, 2)
void attn_kernel(const ushort_t* __restrict__ qb, const char* __restrict__ kbuf,
                 const char* __restrict__ vtb, const ushort_t* __restrict__ m4,
                 ushort_t* __restrict__ attn_o)
{
  __shared__ __align__(16) char smem[32768];
  char* sK = smem;            // 16KB: 64 k-rows x 256B (swizzled)
  char* sV = smem + 16384;    // 16KB: 128 vd-rows x 128B (swizzled)
  const float scale2 = 0.12752081738040466f;  // 128^-0.5 / ln2
  int bid = blockIdx.x;
  bid = (bid & 7) * 128 + (bid >> 3);        // XCD-chunked swizzle (1024 % 8 == 0)
  int qt = bid & 31, bh = bid >> 5;
  int b = bh >> 4, h = bh & 15;
  int tid = threadIdx.x, wave = tid >> 6, lane = tid & 63;
  int l32 = lane & 31, half = lane >> 5;
  int sx = (l32 & 7) << 4;
  int qbase = qt * 64 + wave * 32;

  // Q fragments (B-operand): col = q = l32, k = ks*16 + half*8 + e
  bf16x8 qf[8];
  {
    const ushort_t* qp = qb + (size_t)(b * Sc + qbase + l32) * 2048 + h * 128 + half * 8;
#pragma unroll
    for (int ks = 0; ks < 8; ks++) qf[ks] = *(const bf16x8*)(qp + ks * 16);
  }

  float mrun = -3.0e38f, lrun = 0.f;   // per-lane scalars for q = qbase + l32
  f32x16 acco[4] = {};                  // [vdblk]; rows = q reg-pattern, col = vd

  const char* kg = kbuf + (size_t)bh * 524288;
  const char* vg = vtb + (size_t)bh * 524288;
  const ushort8v* mq = (const ushort8v*)m4 + (size_t)(qbase + l32) * 256 + half * 2;

  for (int kt = 0; kt < 32; kt++) {
    // stage K tile: 16KB linear (global bytes pre-swizzled)
#pragma unroll
    for (int it = 0; it < 8; it++)
      gload16(kg + kt * 16384 + it * 2048 + tid * 16, sK + it * 2048 + tid * 16);
    // stage V^T tile: 16KB, per-vd-row 128B chunks (global bytes pre-swizzled)
#pragma unroll
    for (int it = 0; it < 8; it++) {
      int l = it * 2048 + tid * 16;
      gload16(vg + (size_t)(l >> 7) * 4096 + kt * 128 + (l & 127), sV + l);
    }
    // mask fragments for this tile (4 x 16B, coalesced; latency hides under stage)
    ushort8v mvv[4];
#pragma unroll
    for (int kb = 0; kb < 2; kb++)
#pragma unroll
      for (int rr = 0; rr < 2; rr++)
        mvv[kb * 2 + rr] = mq[kt * 8 + kb * 4 + rr];
    __syncthreads();

#pragma unroll
    for (int kblk = 0; kblk < 2; kblk++) {
      // QK^T (swapped): sc rows = k (32), cols = q (32)
      f32x16 sc = {};
      __builtin_amdgcn_s_setprio(1);
#pragma unroll
      for (int ks = 0; ks < 8; ks++) {
        bf16x8 kfr = *(const bf16x8*)(sK + (kblk * 32 + l32) * 256 +
                                      ((ks * 32 + half * 16) ^ sx));
        sc = MFMA32(kfr, qf[ks], sc, 0, 0, 0);
      }
      __builtin_amdgcn_s_setprio(0);

      // lane-local softmax: lane holds P[q=l32][k = (r&3)+8*(r>>2)+4*half + kblk*32]
#pragma unroll
      for (int r = 0; r < 16; r++)
        sc[r] = sc[r] * scale2 + bf2f(mvv[kblk * 2 + (r >> 3)][r & 7]);
      float mx = sc[0];
#pragma unroll
      for (int r = 1; r < 16; r++) mx = fmaxf(mx, sc[r]);
      mx = fmaxf(mx, __shfl_xor(mx, 32));
      if (!__all(mx <= mrun + 11.0f)) {       // T13 defer-max (rare)
        float mnew = fmaxf(mrun, mx);
        float corr = __builtin_amdgcn_exp2f(mrun - mnew);
        lrun *= corr; mrun = mnew;
#pragma unroll
        for (int r = 0; r < 16; r++) {
          float cr = __shfl(corr, (r & 3) + 8 * (r >> 2) + 4 * half);
#pragma unroll
          for (int vb = 0; vb < 4; vb++) acco[vb][r] *= cr;
        }
      }
      float rs = 0.f;
      uint32_t W[8];
#pragma unroll
      for (int m = 0; m < 4; m++) {
        float p0 = __builtin_amdgcn_exp2f(sc[4 * m + 0] - mrun);
        float p1 = __builtin_amdgcn_exp2f(sc[4 * m + 1] - mrun);
        float p2 = __builtin_amdgcn_exp2f(sc[4 * m + 2] - mrun);
        float p3 = __builtin_amdgcn_exp2f(sc[4 * m + 3] - mrun);
        rs += (p0 + p1) + (p2 + p3);
        W[2 * m] = cvtpk(p0, p1);
        W[2 * m + 1] = cvtpk(p2, p3);
      }
      lrun += rs;   // lane-partial (this half's k); combined in epilogue

      // redistribute P to PV A-frag layout: frag[k2] k = k2*16 + half*8 + e
      bf16x8 pf[2];
#pragma unroll
      for (int k2 = 0; k2 < 2; k2++) {
        uint32_t a0 = W[4 * k2 + 0], a1 = W[4 * k2 + 1];
        uint32_t b0 = W[4 * k2 + 2], b1 = W[4 * k2 + 3];
        plswap(a0, b0);
        plswap(a1, b1);
        u32x4 t; t[0] = a0; t[1] = a1; t[2] = b0; t[3] = b1;
        pf[k2] = __builtin_bit_cast(bf16x8, t);
      }

      // PV: acco[vb] += P(32q x 32k) . V(32k x 128vd)
      __builtin_amdgcn_s_setprio(1);
#pragma unroll
      for (int k2 = 0; k2 < 2; k2++)
#pragma unroll
        for (int vb = 0; vb < 4; vb++) {
          bf16x8 vf = *(const bf16x8*)(sV + (vb * 32 + l32) * 128 +
                                       ((kblk * 64 + k2 * 32 + half * 16) ^ sx));
          acco[vb] = MFMA32(pf[k2], vf, acco[vb], 0, 0, 0);
        }
      __builtin_amdgcn_s_setprio(0);
    }

    __syncthreads();   // all waves done reading sK/sV before next stage
  }

  // epilogue: combine half-partial l, divide, store
  lrun += __shfl_xor(lrun, 32);
#pragma unroll
  for (int r = 0; r < 16; r++) {
    int rowq = (r & 3) + 8 * (r >> 2) + 4 * half;
    float lr = __shfl(lrun, rowq);
    float inv = 1.0f / lr;
    int qrow = qbase + rowq;
    ushort_t* op = attn_o + (size_t)(b * Sc + qrow) * 2048 + h * 128 + l32;
#pragma unroll
    for (int vb = 0; vb < 4; vb++)
      op[vb * 32] = f2bf(acco[vb][r] * inv);
  }
}

extern "C" void kernel_launch(void* const* d_in, const int* in_sizes, int n_in,
                              void* d_out, int out_size, void* d_ws, size_t ws_size,
                              hipStream_t stream) {
  const float* x    = (const float*)d_in[0];
  const float* mask = (const float*)d_in[1];
  const float* Wkvd = (const float*)d_in[2];
  const float* Wkvu = (const float*)d_in[3];
  const float* Wq   = (const float*)d_in[4];
  const float* Wout = (const float*)d_in[5];

  char* ws = (char*)d_ws;
  size_t off = 0;
  auto alloc = [&](size_t bytes) { char* p = ws + off; off += (bytes + 255) & ~(size_t)255; return p; };
  ushort_t* xb   = (ushort_t*)alloc((size_t)4096 * 2048 * 2);
  ushort_t* wkvd = (ushort_t*)alloc((size_t)640 * 2048 * 2);
  ushort_t* wq   = (ushort_t*)alloc((size_t)2048 * 2048 * 2);
  ushort_t* wkvu = (ushort_t*)alloc((size_t)3072 * 512 * 2);
  ushort_t* wout = (ushort_t*)alloc((size_t)2048 * 2048 * 2);
  ushort_t* comp = (ushort_t*)alloc((size_t)4096 * 640 * 2);
  ushort_t* qbuf = (ushort_t*)alloc((size_t)4096 * 2048 * 2);
  char*     kbuf = alloc((size_t)Bc * Hc * Sc * 256);
  char*     vtb  = alloc((size_t)Bc * Hc * 524288);
  ushort_t* attn_o = xb;   // xb dead after q-GEMM; reuse
  ushort_t* m4 = wq;       // wq dead after q-GEMM; reuse (8MB)

  // all casts in one launch
  cast_all<<<19200, 256, 0, stream>>>(x, Wq, Wkvu, Wout, Wkvd, xb, wq, wkvu, wout, wkvd);

  // compressed = x . W_kv_down^T  (N padded 576->640; 128^2 path)
  gemm_bt<0><<<32 * 5, 256, 0, stream>>>(xb, 2048, wkvd, 2048, comp, 640, 4096, 640, 2048, nullptr, nullptr);
  // q = x . W_q^T  (256^2 deep-pipelined path)
  gemm256<0><<<128, 512, 0, stream>>>(xb, wq, qbuf, 4096, 2048, 2048);
  // mask -> 32x32 swapped fragment order + rope broadcast into kbuf (merged)
  prep_kernel<<<2176, 256, 0, stream>>>(mask, m4, comp, kbuf);
  // kv_exp = kv_c . W_kv_up^T, scattered into vT(swizzled) + kbuf(nope, swizzled)
  gemm_bt<1><<<32 * 24, 256, 0, stream>>>(comp, 640, wkvu, 512, nullptr, 0, 4096, 3072, 512, vtb, kbuf);
  // flash attention (round-6 structure: best measured, 113.5 us)
  attn_kernel<<<1024, 128, 0, stream>>>(qbuf, kbuf, vtb, m4, attn_o);
  // out = attn . W_out^T (f32 store; 256^2 deep-pipelined path)
  gemm256<2><<<128, 512, 0, stream>>>(attn_o, wout, d_out, 4096, 2048, 2048);
}

// Round 16
// 272.763 us; speedup vs baseline: 1.1229x; 1.1229x over previous
//
#include <hip/hip_runtime.h>
#include <hip/hip_bf16.h>
#include <stdint.h>

typedef __bf16 bf16x8 __attribute__((ext_vector_type(8)));
typedef float f32x4 __attribute__((ext_vector_type(4)));
typedef float f32x16 __attribute__((ext_vector_type(16)));
typedef uint32_t u32x4 __attribute__((ext_vector_type(4)));
typedef unsigned short ushort_t;
typedef unsigned short ushort8v __attribute__((ext_vector_type(8)));

#define MFMA16 __builtin_amdgcn_mfma_f32_16x16x32_bf16
#define MFMA32 __builtin_amdgcn_mfma_f32_32x32x16_bf16

static constexpr int Bc = 2, Sc = 2048, Ec = 2048, Hc = 16;

__device__ __forceinline__ void gload16(const void* g, void* l) {
  __builtin_amdgcn_global_load_lds(
      (const __attribute__((address_space(1))) void*)g,
      (__attribute__((address_space(3))) void*)l, 16, 0, 0);
}

__device__ __forceinline__ ushort_t f2bf(float f) {
  uint32_t u = __float_as_uint(f);
  uint32_t r = (u + 0x7fffu + ((u >> 16) & 1u)) >> 16;
  return (ushort_t)r;
}
__device__ __forceinline__ float bf2f(ushort_t u) {
  return __uint_as_float((uint32_t)u << 16);
}
__device__ __forceinline__ uint32_t cvtpk(float a, float b) {
  uint32_t d;
  asm("v_cvt_pk_bf16_f32 %0, %1, %2" : "=v"(d) : "v"(a), "v"(b));
  return d;
}
// exchange: a[lanes 32..63] <-> b[lanes 0..31]
__device__ __forceinline__ void plswap(uint32_t& a, uint32_t& b) {
  asm("v_permlane32_swap_b32 %0, %1" : "+v"(a), "+v"(b));
}

// ---------------- fused casts: all 5 weight/x tensors in one launch ----------------
__global__ void cast_all(const float* __restrict__ x, const float* __restrict__ Wq,
                         const float* __restrict__ Wkvu, const float* __restrict__ Wout,
                         const float* __restrict__ Wkvd,
                         ushort_t* __restrict__ xb, ushort_t* __restrict__ wq,
                         ushort_t* __restrict__ wkvu, ushort_t* __restrict__ wout,
                         ushort_t* __restrict__ wkvd) {
  int i = blockIdx.x * 256 + threadIdx.x;
  const float* src;
  ushort_t* dst;
  int j;
  if (i < 2097152) { src = x; dst = xb; j = i; }
  else if (i < 3145728) { src = Wq; dst = wq; j = i - 2097152; }
  else if (i < 3538944) { src = Wkvu; dst = wkvu; j = i - 3145728; }
  else if (i < 4587520) { src = Wout; dst = wout; j = i - 3538944; }
  else {
    j = i - 4587520;                      // wkvd with row pad 576->640
    int row = j >> 9, col4 = j & 511;
    ushort4 o;
    if (row < 576) {
      float4 v = ((const float4*)Wkvd)[row * 512 + col4];
      o.x = f2bf(v.x); o.y = f2bf(v.y); o.z = f2bf(v.z); o.w = f2bf(v.w);
    } else { o.x = 0; o.y = 0; o.z = 0; o.w = 0; }
    ((ushort4*)wkvd)[j] = o;
    return;
  }
  float4 v = ((const float4*)src)[j];
  ushort4 o;
  o.x = f2bf(v.x); o.y = f2bf(v.y); o.z = f2bf(v.z); o.w = f2bf(v.w);
  ((ushort4*)dst)[j] = o;
}

// ---------------- prep: mask rearrange (blocks 0..2047) + rope_fill (blocks 2048..2175) ----------------
// mask: ushort8 unit u = q*256 + kt*8 + kblk*4 + half*2 + rr
//   element j = mask[q][kt*64 + kblk*32 + 4*half + (j&3) + 8*(2*rr+(j>>2))] / ln2
__global__ void prep_kernel(const float* __restrict__ mask, ushort_t* __restrict__ m4,
                            const ushort_t* __restrict__ comp, char* __restrict__ kbuf) {
  const float INVLN2 = 1.4426950408889634f;
  int gb = blockIdx.x;
  if (gb < 2048) {
    int i = gb * 256 + threadIdx.x;   // 524288 units
    int rr = i & 1, half = (i >> 1) & 1, kblk = (i >> 2) & 1, kt = (i >> 3) & 31, q = i >> 8;
    const float* src = mask + (size_t)q * 2048 + kt * 64 + kblk * 32 + half * 4 + rr * 16;
    float4 a = *(const float4*)src;         // j=0..3
    float4 c = *(const float4*)(src + 8);   // j=4..7
    ushort8v o;
    o[0] = f2bf(a.x * INVLN2); o[1] = f2bf(a.y * INVLN2);
    o[2] = f2bf(a.z * INVLN2); o[3] = f2bf(a.w * INVLN2);
    o[4] = f2bf(c.x * INVLN2); o[5] = f2bf(c.y * INVLN2);
    o[6] = f2bf(c.z * INVLN2); o[7] = f2bf(c.w * INVLN2);
    ((ushort8v*)m4)[i] = o;
  } else {
    int i = (gb - 2048) * 256 + threadIdx.x;  // B*S*8 = 32768 16-byte blocks
    int blk = i & 7;
    int m = i >> 3;
    int s = m & 2047, b = m >> 11;
    uint4 v = *(const uint4*)&comp[(size_t)m * 640 + 512 + blk * 8];
    int off = (blk * 16) ^ ((s & 7) << 4);
#pragma unroll
    for (int h = 0; h < Hc; h++) {
      *(uint4*)(kbuf + ((size_t)(b * Hc + h) * Sc + s) * 256 + off) = v;
    }
  }
}

// ---------------- GEMM 128x128, BK=64 (round-9 structure) — used for kv-down + kv-up ----------------
template<int MODE>
__global__ __launch_bounds__(256, 2)
void gemm_bt(const ushort_t* __restrict__ A, int lda,
             const ushort_t* __restrict__ Bm, int ldb,
             void* __restrict__ Cout, int ldc,
             int M, int N, int K,
             char* __restrict__ vtb, char* __restrict__ kbuf)
{
  __shared__ __align__(16) ushort_t sA[2][128 * 32];
  __shared__ __align__(16) ushort_t sB[2][128 * 32];
  int tid = threadIdx.x;
  int nTn = N >> 7;
  int bid = blockIdx.x;
  int chunk = gridDim.x >> 3;                       // grids are %8==0 -> bijective
  bid = (bid & 7) * chunk + (bid >> 3);             // XCD-chunked swizzle
  int tm = bid / nTn, tn = bid - tm * nTn;
  int wave = tid >> 6, lane = tid & 63;
  int wm = (wave >> 1) << 6, wn = (wave & 1) << 6;
  int l16 = lane & 15, g16 = lane >> 4;
  f32x4 acc[4][4] = {};
  int srow = tid >> 2, scol = (tid & 3) << 3;
  const ushort_t* Ag = A + (size_t)(tm * 128 + srow) * lda + scol;
  const ushort_t* Bg = Bm + (size_t)(tn * 128 + srow) * ldb + scol;
  ushort_t* sA0 = &sA[0][srow * 32 + scol];
  ushort_t* sA1 = &sA[1][srow * 32 + scol];
  ushort_t* sB0 = &sB[0][srow * 32 + scol];
  ushort_t* sB1 = &sB[1][srow * 32 + scol];
  for (int kt = 0; kt < K; kt += 64) {
    gload16(Ag, sA0);
    gload16(Ag + (size_t)64 * lda, sA0 + 64 * 32);
    gload16(Ag + 32, sA1);
    gload16(Ag + (size_t)64 * lda + 32, sA1 + 64 * 32);
    gload16(Bg, sB0);
    gload16(Bg + (size_t)64 * ldb, sB0 + 64 * 32);
    gload16(Bg + 32, sB1);
    gload16(Bg + (size_t)64 * ldb + 32, sB1 + 64 * 32);
    Ag += 64; Bg += 64;
    __syncthreads();
#pragma unroll
    for (int h2 = 0; h2 < 2; h2++) {
      bf16x8 af[4], bfr[4];
#pragma unroll
      for (int i = 0; i < 4; i++) af[i] = *(const bf16x8*)&sA[h2][(wm + i * 16 + l16) * 32 + g16 * 8];
#pragma unroll
      for (int i = 0; i < 4; i++) bfr[i] = *(const bf16x8*)&sB[h2][(wn + i * 16 + l16) * 32 + g16 * 8];
#pragma unroll
      for (int i = 0; i < 4; i++)
#pragma unroll
        for (int j = 0; j < 4; j++)
          acc[i][j] = MFMA16(af[i], bfr[j], acc[i][j], 0, 0, 0);
    }
    __syncthreads();
  }
  // epilogue: C/D layout col=lane&15, row=(lane>>4)*4+r
#pragma unroll
  for (int i = 0; i < 4; i++) {
#pragma unroll
    for (int j = 0; j < 4; j++) {
      int grow0 = tm * 128 + wm + i * 16 + g16 * 4;
      int gcol = tn * 128 + wn + j * 16 + l16;
      if constexpr (MODE == 0) {
#pragma unroll
        for (int r = 0; r < 4; r++)
          ((ushort_t*)Cout)[(size_t)(grow0 + r) * ldc + gcol] = f2bf(acc[i][j][r]);
      } else {
        int h = gcol / 192, jj = gcol - h * 192;
        int b = grow0 >> 11, s0 = grow0 & 2047;
        size_t bh = (size_t)(b * Hc + h);
        if (jj < 128) {
          // V^T, pre-swizzled; 4 consecutive s -> one 8B store (s0 %4==0, same 64-chunk)
          ushort4 pk;
          pk.x = f2bf(acc[i][j][0]); pk.y = f2bf(acc[i][j][1]);
          pk.z = f2bf(acc[i][j][2]); pk.w = f2bf(acc[i][j][3]);
          *(ushort4*)(vtb + bh * 524288 + (size_t)jj * 4096 + ((s0 >> 6) * 128) +
                      ((2 * (s0 & 63)) ^ ((jj & 7) << 4))) = pk;
        } else {
          int col = 64 + (jj - 128);                    // nope -> k dims 64..127
#pragma unroll
          for (int r = 0; r < 4; r++) {
            int s = s0 + r;
            *(ushort_t*)(kbuf + (bh * Sc + s) * 256 + ((2 * col) ^ ((s & 7) << 4))) = f2bf(acc[i][j][r]);
          }
        }
      }
    }
  }
}

// ---------------- GEMM 256x128, BK=64, deep-pipelined — q-GEMM and out-GEMM ----------------
// 512 thr = 8 waves (4M x 2N); LDS 96KB dbuf (1 block/CU, 8 waves); 1 barrier per K-tile;
// prefetch issued right after the barrier -> next barrier's drain waits on K-tile-old loads.
// T2 swizzle (rule #21): linear gload_lds dest + inverse-swizzled per-lane global source
// column + swizzled ds_read address. Grid 16x16 = 256 blocks = full chip (fixes round-15's
// 128-block half-chip occupancy).
template<int OUTF>   // 0 = bf16 store, 2 = f32 store
__global__ __launch_bounds__(512, 2)
void gemm256(const ushort_t* __restrict__ A, const ushort_t* __restrict__ Bm,
             void* __restrict__ Cout, int M, int N, int K)
{
  __shared__ __align__(16) ushort_t sA[2][256 * 64];
  __shared__ __align__(16) ushort_t sB[2][128 * 64];
  int tid = threadIdx.x;
  int nTn = N >> 7;
  int bid = blockIdx.x;
  int chunk = gridDim.x >> 3;                       // grid %8==0 -> bijective
  bid = (bid & 7) * chunk + (bid >> 3);             // XCD-chunked swizzle
  int tm = bid / nTn, tn = bid - tm * nTn;
  int wave = tid >> 6, lane = tid & 63;
  int wm = wave >> 1, wn = wave & 1;                // 4M x 2N wave grid, 64x64 each
  int l16 = lane & 15, g16 = lane >> 4;
  f32x4 acc[4][4] = {};

  // staging: row = it*64 + (tid>>3) (row&7 invariant across it); col pre-swizzled
  int srow0 = tid >> 3;            // 0..63
  int colsw = ((tid & 7) ^ (srow0 & 7)) * 8;        // element offset
  const ushort_t* Ag = A + (size_t)(tm * 256 + srow0) * K + colsw;
  const ushort_t* Bg = Bm + (size_t)(tn * 128 + srow0) * K + colsw;

  auto ISSUE = [&](int kk, int nb) {
#pragma unroll
    for (int it = 0; it < 4; it++)
      gload16(Ag + (size_t)(it * 64) * K + kk, (char*)sA[nb] + it * 8192 + tid * 16);
#pragma unroll
    for (int it = 0; it < 2; it++)
      gload16(Bg + (size_t)(it * 64) * K + kk, (char*)sB[nb] + it * 8192 + tid * 16);
  };

  ISSUE(0, 0);
  int Kt = K >> 6;
  int csw = (l16 & 7) << 4;
  for (int kt = 0; kt < Kt; kt++) {
    int buf = kt & 1;
    __syncthreads();               // drains this tile's loads (issued one K-tile ago)
    if (kt + 1 < Kt) ISSUE((kt + 1) * 64, buf ^ 1);
    const char* bA = (const char*)sA[buf];
    const char* bB = (const char*)sB[buf];
#pragma unroll
    for (int ks = 0; ks < 2; ks++) {
      int c = (ks * 64 + g16 * 16) ^ csw;           // byte offset in 128B row
      bf16x8 bf[4], af[4];
#pragma unroll
      for (int j = 0; j < 4; j++)
        bf[j] = *(const bf16x8*)(bB + (wn * 64 + j * 16 + l16) * 128 + c);
#pragma unroll
      for (int i = 0; i < 4; i++)
        af[i] = *(const bf16x8*)(bA + (wm * 64 + i * 16 + l16) * 128 + c);
      __builtin_amdgcn_s_setprio(1);
#pragma unroll
      for (int i = 0; i < 4; i++)
#pragma unroll
        for (int j = 0; j < 4; j++)
          acc[i][j] = MFMA16(af[i], bf[j], acc[i][j], 0, 0, 0);
      __builtin_amdgcn_s_setprio(0);
    }
  }
  // epilogue: C/D layout col=lane&15, row=(lane>>4)*4+r
#pragma unroll
  for (int i = 0; i < 4; i++) {
#pragma unroll
    for (int j = 0; j < 4; j++) {
      int grow0 = tm * 256 + wm * 64 + i * 16 + g16 * 4;
      int gcol = tn * 128 + wn * 64 + j * 16 + l16;
#pragma unroll
      for (int r = 0; r < 4; r++) {
        if constexpr (OUTF == 0)
          ((ushort_t*)Cout)[(size_t)(grow0 + r) * N + gcol] = f2bf(acc[i][j][r]);
        else
          ((float*)Cout)[(size_t)(grow0 + r) * N + gcol] = acc[i][j][r];
      }
    }
  }
}

// ---------------- flash attention, 32x32 MFMA + swapped QK^T + in-register P (round-6, best) ----------------
__global__ __launch_bounds__(128, 2)
void attn_kernel(const ushort_t* __restrict__ qb, const char* __restrict__ kbuf,
                 const char* __restrict__ vtb, const ushort_t* __restrict__ m4,
                 ushort_t* __restrict__ attn_o)
{
  __shared__ __align__(16) char smem[32768];
  char* sK = smem;            // 16KB: 64 k-rows x 256B (swizzled)
  char* sV = smem + 16384;    // 16KB: 128 vd-rows x 128B (swizzled)
  const float scale2 = 0.12752081738040466f;  // 128^-0.5 / ln2
  int bid = blockIdx.x;
  bid = (bid & 7) * 128 + (bid >> 3);        // XCD-chunked swizzle (1024 % 8 == 0)
  int qt = bid & 31, bh = bid >> 5;
  int b = bh >> 4, h = bh & 15;
  int tid = threadIdx.x, wave = tid >> 6, lane = tid & 63;
  int l32 = lane & 31, half = lane >> 5;
  int sx = (l32 & 7) << 4;
  int qbase = qt * 64 + wave * 32;

  // Q fragments (B-operand): col = q = l32, k = ks*16 + half*8 + e
  bf16x8 qf[8];
  {
    const ushort_t* qp = qb + (size_t)(b * Sc + qbase + l32) * 2048 + h * 128 + half * 8;
#pragma unroll
    for (int ks = 0; ks < 8; ks++) qf[ks] = *(const bf16x8*)(qp + ks * 16);
  }

  float mrun = -3.0e38f, lrun = 0.f;   // per-lane scalars for q = qbase + l32
  f32x16 acco[4] = {};                  // [vdblk]; rows = q reg-pattern, col = vd

  const char* kg = kbuf + (size_t)bh * 524288;
  const char* vg = vtb + (size_t)bh * 524288;
  const ushort8v* mq = (const ushort8v*)m4 + (size_t)(qbase + l32) * 256 + half * 2;

  for (int kt = 0; kt < 32; kt++) {
    // stage K tile: 16KB linear (global bytes pre-swizzled)
#pragma unroll
    for (int it = 0; it < 8; it++)
      gload16(kg + kt * 16384 + it * 2048 + tid * 16, sK + it * 2048 + tid * 16);
    // stage V^T tile: 16KB, per-vd-row 128B chunks (global bytes pre-swizzled)
#pragma unroll
    for (int it = 0; it < 8; it++) {
      int l = it * 2048 + tid * 16;
      gload16(vg + (size_t)(l >> 7) * 4096 + kt * 128 + (l & 127), sV + l);
    }
    // mask fragments for this tile (4 x 16B, coalesced; latency hides under stage)
    ushort8v mvv[4];
#pragma unroll
    for (int kb = 0; kb < 2; kb++)
#pragma unroll
      for (int rr = 0; rr < 2; rr++)
        mvv[kb * 2 + rr] = mq[kt * 8 + kb * 4 + rr];
    __syncthreads();

#pragma unroll
    for (int kblk = 0; kblk < 2; kblk++) {
      // QK^T (swapped): sc rows = k (32), cols = q (32)
      f32x16 sc = {};
      __builtin_amdgcn_s_setprio(1);
#pragma unroll
      for (int ks = 0; ks < 8; ks++) {
        bf16x8 kfr = *(const bf16x8*)(sK + (kblk * 32 + l32) * 256 +
                                      ((ks * 32 + half * 16) ^ sx));
        sc = MFMA32(kfr, qf[ks], sc, 0, 0, 0);
      }
      __builtin_amdgcn_s_setprio(0);

      // lane-local softmax: lane holds P[q=l32][k = (r&3)+8*(r>>2)+4*half + kblk*32]
#pragma unroll
      for (int r = 0; r < 16; r++)
        sc[r] = sc[r] * scale2 + bf2f(mvv[kblk * 2 + (r >> 3)][r & 7]);
      float mx = sc[0];
#pragma unroll
      for (int r = 1; r < 16; r++) mx = fmaxf(mx, sc[r]);
      mx = fmaxf(mx, __shfl_xor(mx, 32));
      if (!__all(mx <= mrun + 11.0f)) {       // T13 defer-max (rare)
        float mnew = fmaxf(mrun, mx);
        float corr = __builtin_amdgcn_exp2f(mrun - mnew);
        lrun *= corr; mrun = mnew;
#pragma unroll
        for (int r = 0; r < 16; r++) {
          float cr = __shfl(corr, (r & 3) + 8 * (r >> 2) + 4 * half);
#pragma unroll
          for (int vb = 0; vb < 4; vb++) acco[vb][r] *= cr;
        }
      }
      float rs = 0.f;
      uint32_t W[8];
#pragma unroll
      for (int m = 0; m < 4; m++) {
        float p0 = __builtin_amdgcn_exp2f(sc[4 * m + 0] - mrun);
        float p1 = __builtin_amdgcn_exp2f(sc[4 * m + 1] - mrun);
        float p2 = __builtin_amdgcn_exp2f(sc[4 * m + 2] - mrun);
        float p3 = __builtin_amdgcn_exp2f(sc[4 * m + 3] - mrun);
        rs += (p0 + p1) + (p2 + p3);
        W[2 * m] = cvtpk(p0, p1);
        W[2 * m + 1] = cvtpk(p2, p3);
      }
      lrun += rs;   // lane-partial (this half's k); combined in epilogue

      // redistribute P to PV A-frag layout: frag[k2] k = k2*16 + half*8 + e
      bf16x8 pf[2];
#pragma unroll
      for (int k2 = 0; k2 < 2; k2++) {
        uint32_t a0 = W[4 * k2 + 0], a1 = W[4 * k2 + 1];
        uint32_t b0 = W[4 * k2 + 2], b1 = W[4 * k2 + 3];
        plswap(a0, b0);
        plswap(a1, b1);
        u32x4 t; t[0] = a0; t[1] = a1; t[2] = b0; t[3] = b1;
        pf[k2] = __builtin_bit_cast(bf16x8, t);
      }

      // PV: acco[vb] += P(32q x 32k) . V(32k x 128vd)
      __builtin_amdgcn_s_setprio(1);
#pragma unroll
      for (int k2 = 0; k2 < 2; k2++)
#pragma unroll
        for (int vb = 0; vb < 4; vb++) {
          bf16x8 vf = *(const bf16x8*)(sV + (vb * 32 + l32) * 128 +
                                       ((kblk * 64 + k2 * 32 + half * 16) ^ sx));
          acco[vb] = MFMA32(pf[k2], vf, acco[vb], 0, 0, 0);
        }
      __builtin_amdgcn_s_setprio(0);
    }

    __syncthreads();   // all waves done reading sK/sV before next stage
  }

  // epilogue: combine half-partial l, divide, store
  lrun += __shfl_xor(lrun, 32);
#pragma unroll
  for (int r = 0; r < 16; r++) {
    int rowq = (r & 3) + 8 * (r >> 2) + 4 * half;
    float lr = __shfl(lrun, rowq);
    float inv = 1.0f / lr;
    int qrow = qbase + rowq;
    ushort_t* op = attn_o + (size_t)(b * Sc + qrow) * 2048 + h * 128 + l32;
#pragma unroll
    for (int vb = 0; vb < 4; vb++)
      op[vb * 32] = f2bf(acco[vb][r] * inv);
  }
}

extern "C" void kernel_launch(void* const* d_in, const int* in_sizes, int n_in,
                              void* d_out, int out_size, void* d_ws, size_t ws_size,
                              hipStream_t stream) {
  const float* x    = (const float*)d_in[0];
  const float* mask = (const float*)d_in[1];
  const float* Wkvd = (const float*)d_in[2];
  const float* Wkvu = (const float*)d_in[3];
  const float* Wq   = (const float*)d_in[4];
  const float* Wout = (const float*)d_in[5];

  char* ws = (char*)d_ws;
  size_t off = 0;
  auto alloc = [&](size_t bytes) { char* p = ws + off; off += (bytes + 255) & ~(size_t)255; return p; };
  ushort_t* xb   = (ushort_t*)alloc((size_t)4096 * 2048 * 2);
  ushort_t* wkvd = (ushort_t*)alloc((size_t)640 * 2048 * 2);
  ushort_t* wq   = (ushort_t*)alloc((size_t)2048 * 2048 * 2);
  ushort_t* wkvu = (ushort_t*)alloc((size_t)3072 * 512 * 2);
  ushort_t* wout = (ushort_t*)alloc((size_t)2048 * 2048 * 2);
  ushort_t* comp = (ushort_t*)alloc((size_t)4096 * 640 * 2);
  ushort_t* qbuf = (ushort_t*)alloc((size_t)4096 * 2048 * 2);
  char*     kbuf = alloc((size_t)Bc * Hc * Sc * 256);
  char*     vtb  = alloc((size_t)Bc * Hc * 524288);
  ushort_t* attn_o = xb;   // xb dead after q-GEMM; reuse
  ushort_t* m4 = wq;       // wq dead after q-GEMM; reuse (8MB)

  // all casts in one launch
  cast_all<<<19200, 256, 0, stream>>>(x, Wq, Wkvu, Wout, Wkvd, xb, wq, wkvu, wout, wkvd);

  // compressed = x . W_kv_down^T  (N padded 576->640; 128^2 path)
  gemm_bt<0><<<32 * 5, 256, 0, stream>>>(xb, 2048, wkvd, 2048, comp, 640, 4096, 640, 2048, nullptr, nullptr);
  // q = x . W_q^T  (256x128 deep-pipelined path, 256 blocks = full chip)
  gemm256<0><<<256, 512, 0, stream>>>(xb, wq, qbuf, 4096, 2048, 2048);
  // mask -> 32x32 swapped fragment order + rope broadcast into kbuf (merged)
  prep_kernel<<<2176, 256, 0, stream>>>(mask, m4, comp, kbuf);
  // kv_exp = kv_c . W_kv_up^T, scattered into vT(swizzled) + kbuf(nope, swizzled)
  gemm_bt<1><<<32 * 24, 256, 0, stream>>>(comp, 640, wkvu, 512, nullptr, 0, 4096, 3072, 512, vtb, kbuf);
  // flash attention (round-6 structure: best measured, 113.5 us)
  attn_kernel<<<1024, 128, 0, stream>>>(qbuf, kbuf, vtb, m4, attn_o);
  // out = attn . W_out^T (f32 store; 256x128 deep-pipelined path)
  gemm256<2><<<256, 512, 0, stream>>>(attn_o, wout, d_out, 4096, 2048, 2048);
}

// Round 17
// 263.137 us; speedup vs baseline: 1.1639x; 1.0366x over previous
//
#include <hip/hip_runtime.h>
#include <hip/hip_bf16.h>
#include <stdint.h>

typedef __bf16 bf16x8 __attribute__((ext_vector_type(8)));
typedef float f32x4 __attribute__((ext_vector_type(4)));
typedef float f32x16 __attribute__((ext_vector_type(16)));
typedef uint32_t u32x4 __attribute__((ext_vector_type(4)));
typedef unsigned short ushort_t;
typedef unsigned short ushort8v __attribute__((ext_vector_type(8)));

#define MFMA16 __builtin_amdgcn_mfma_f32_16x16x32_bf16
#define MFMA32 __builtin_amdgcn_mfma_f32_32x32x16_bf16

static constexpr int Bc = 2, Sc = 2048, Ec = 2048, Hc = 16;

__device__ __forceinline__ void gload16(const void* g, void* l) {
  __builtin_amdgcn_global_load_lds(
      (const __attribute__((address_space(1))) void*)g,
      (__attribute__((address_space(3))) void*)l, 16, 0, 0);
}

__device__ __forceinline__ ushort_t f2bf(float f) {
  uint32_t u = __float_as_uint(f);
  uint32_t r = (u + 0x7fffu + ((u >> 16) & 1u)) >> 16;
  return (ushort_t)r;
}
__device__ __forceinline__ float bf2f(ushort_t u) {
  return __uint_as_float((uint32_t)u << 16);
}
__device__ __forceinline__ uint32_t cvtpk(float a, float b) {
  uint32_t d;
  asm("v_cvt_pk_bf16_f32 %0, %1, %2" : "=v"(d) : "v"(a), "v"(b));
  return d;
}
// exchange: a[lanes 32..63] <-> b[lanes 0..31]
__device__ __forceinline__ void plswap(uint32_t& a, uint32_t& b) {
  asm("v_permlane32_swap_b32 %0, %1" : "+v"(a), "+v"(b));
}

// ---------------- fused casts: all 5 weight/x tensors in one launch ----------------
__global__ void cast_all(const float* __restrict__ x, const float* __restrict__ Wq,
                         const float* __restrict__ Wkvu, const float* __restrict__ Wout,
                         const float* __restrict__ Wkvd,
                         ushort_t* __restrict__ xb, ushort_t* __restrict__ wq,
                         ushort_t* __restrict__ wkvu, ushort_t* __restrict__ wout,
                         ushort_t* __restrict__ wkvd) {
  int i = blockIdx.x * 256 + threadIdx.x;
  const float* src;
  ushort_t* dst;
  int j;
  if (i < 2097152) { src = x; dst = xb; j = i; }
  else if (i < 3145728) { src = Wq; dst = wq; j = i - 2097152; }
  else if (i < 3538944) { src = Wkvu; dst = wkvu; j = i - 3145728; }
  else if (i < 4587520) { src = Wout; dst = wout; j = i - 3538944; }
  else {
    j = i - 4587520;                      // wkvd with row pad 576->640
    int row = j >> 9, col4 = j & 511;
    ushort4 o;
    if (row < 576) {
      float4 v = ((const float4*)Wkvd)[row * 512 + col4];
      o.x = f2bf(v.x); o.y = f2bf(v.y); o.z = f2bf(v.z); o.w = f2bf(v.w);
    } else { o.x = 0; o.y = 0; o.z = 0; o.w = 0; }
    ((ushort4*)wkvd)[j] = o;
    return;
  }
  float4 v = ((const float4*)src)[j];
  ushort4 o;
  o.x = f2bf(v.x); o.y = f2bf(v.y); o.z = f2bf(v.z); o.w = f2bf(v.w);
  ((ushort4*)dst)[j] = o;
}

// ---------------- mask rearrange for 32x32 swapped layout ----------------
// ushort8 unit index u = q*256 + kt*8 + kblk*4 + half*2 + rr
// element j: value = mask[q][kt*64 + kblk*32 + 4*half + (j&3) + 8*(2*rr+(j>>2))] / ln2
__global__ void mask_rearrange(const float* __restrict__ mask, ushort_t* __restrict__ m4) {
  const float INVLN2 = 1.4426950408889634f;
  int i = blockIdx.x * 256 + threadIdx.x;   // 524288 units
  if (i >= 524288) return;
  int rr = i & 1, half = (i >> 1) & 1, kblk = (i >> 2) & 1, kt = (i >> 3) & 31, q = i >> 8;
  const float* src = mask + (size_t)q * 2048 + kt * 64 + kblk * 32 + half * 4 + rr * 16;
  float4 a = *(const float4*)src;         // j=0..3
  float4 c = *(const float4*)(src + 8);   // j=4..7
  ushort8v o;
  o[0] = f2bf(a.x * INVLN2); o[1] = f2bf(a.y * INVLN2);
  o[2] = f2bf(a.z * INVLN2); o[3] = f2bf(a.w * INVLN2);
  o[4] = f2bf(c.x * INVLN2); o[5] = f2bf(c.y * INVLN2);
  o[6] = f2bf(c.z * INVLN2); o[7] = f2bf(c.w * INVLN2);
  ((ushort8v*)m4)[i] = o;
}

// ---------------- GEMM: C[m][n] = sum_k A[m][k]*B[n][k], 128x128 tiles, BK=64 ----------------
// Round-9 verified structure: 32KB LDS, two K-slices per barrier period, 4-5 blocks/CU.
template<int MODE>
__global__ __launch_bounds__(256, 2)
void gemm_bt(const ushort_t* __restrict__ A, int lda,
             const ushort_t* __restrict__ Bm, int ldb,
             void* __restrict__ Cout, int ldc,
             int M, int N, int K,
             char* __restrict__ vtb, char* __restrict__ kbuf)
{
  __shared__ __align__(16) ushort_t sA[2][128 * 32];
  __shared__ __align__(16) ushort_t sB[2][128 * 32];
  int tid = threadIdx.x;
  int nTn = N >> 7;
  int bid = blockIdx.x;
  int chunk = gridDim.x >> 3;                       // grids are %8==0 -> bijective
  bid = (bid & 7) * chunk + (bid >> 3);             // XCD-chunked swizzle
  int tm = bid / nTn, tn = bid - tm * nTn;
  int wave = tid >> 6, lane = tid & 63;
  int wm = (wave >> 1) << 6, wn = (wave & 1) << 6;
  int l16 = lane & 15, g16 = lane >> 4;
  f32x4 acc[4][4] = {};
  int srow = tid >> 2, scol = (tid & 3) << 3;
  const ushort_t* Ag = A + (size_t)(tm * 128 + srow) * lda + scol;
  const ushort_t* Bg = Bm + (size_t)(tn * 128 + srow) * ldb + scol;
  ushort_t* sA0 = &sA[0][srow * 32 + scol];
  ushort_t* sA1 = &sA[1][srow * 32 + scol];
  ushort_t* sB0 = &sB[0][srow * 32 + scol];
  ushort_t* sB1 = &sB[1][srow * 32 + scol];
  for (int kt = 0; kt < K; kt += 64) {
    gload16(Ag, sA0);
    gload16(Ag + (size_t)64 * lda, sA0 + 64 * 32);
    gload16(Ag + 32, sA1);
    gload16(Ag + (size_t)64 * lda + 32, sA1 + 64 * 32);
    gload16(Bg, sB0);
    gload16(Bg + (size_t)64 * ldb, sB0 + 64 * 32);
    gload16(Bg + 32, sB1);
    gload16(Bg + (size_t)64 * ldb + 32, sB1 + 64 * 32);
    Ag += 64; Bg += 64;
    __syncthreads();
#pragma unroll
    for (int h2 = 0; h2 < 2; h2++) {
      bf16x8 af[4], bfr[4];
#pragma unroll
      for (int i = 0; i < 4; i++) af[i] = *(const bf16x8*)&sA[h2][(wm + i * 16 + l16) * 32 + g16 * 8];
#pragma unroll
      for (int i = 0; i < 4; i++) bfr[i] = *(const bf16x8*)&sB[h2][(wn + i * 16 + l16) * 32 + g16 * 8];
#pragma unroll
      for (int i = 0; i < 4; i++)
#pragma unroll
        for (int j = 0; j < 4; j++)
          acc[i][j] = MFMA16(af[i], bfr[j], acc[i][j], 0, 0, 0);
    }
    __syncthreads();
  }
  // epilogue: C/D layout col=lane&15, row=(lane>>4)*4+r
#pragma unroll
  for (int i = 0; i < 4; i++) {
#pragma unroll
    for (int j = 0; j < 4; j++) {
      int grow0 = tm * 128 + wm + i * 16 + g16 * 4;
      int gcol = tn * 128 + wn + j * 16 + l16;
      if constexpr (MODE == 0) {
#pragma unroll
        for (int r = 0; r < 4; r++)
          ((ushort_t*)Cout)[(size_t)(grow0 + r) * ldc + gcol] = f2bf(acc[i][j][r]);
      } else if constexpr (MODE == 2) {
#pragma unroll
        for (int r = 0; r < 4; r++)
          ((float*)Cout)[(size_t)(grow0 + r) * ldc + gcol] = acc[i][j][r];
      } else {
        int h = gcol / 192, jj = gcol - h * 192;
        int b = grow0 >> 11, s0 = grow0 & 2047;
        size_t bh = (size_t)(b * Hc + h);
        if (jj < 128) {
          // V^T, pre-swizzled; 4 consecutive s -> one 8B store (s0 %4==0, same 64-chunk)
          ushort4 pk;
          pk.x = f2bf(acc[i][j][0]); pk.y = f2bf(acc[i][j][1]);
          pk.z = f2bf(acc[i][j][2]); pk.w = f2bf(acc[i][j][3]);
          *(ushort4*)(vtb + bh * 524288 + (size_t)jj * 4096 + ((s0 >> 6) * 128) +
                      ((2 * (s0 & 63)) ^ ((jj & 7) << 4))) = pk;
        } else {
          int col = 64 + (jj - 128);                    // nope -> k dims 64..127
#pragma unroll
          for (int r = 0; r < 4; r++) {
            int s = s0 + r;
            *(ushort_t*)(kbuf + (bh * Sc + s) * 256 + ((2 * col) ^ ((s & 7) << 4))) = f2bf(acc[i][j][r]);
          }
        }
      }
    }
  }
}

// ---------------- broadcast k_rope into kbuf (swizzled byte layout) ----------------
__global__ void rope_fill(const ushort_t* __restrict__ comp, char* __restrict__ kbuf) {
  int i = blockIdx.x * 256 + threadIdx.x;  // over B*S*8 16-byte blocks
  if (i >= Bc * Sc * 8) return;
  int blk = i & 7;
  int m = i >> 3;
  int s = m & 2047, b = m >> 11;
  uint4 v = *(const uint4*)&comp[(size_t)m * 640 + 512 + blk * 8];
  int off = (blk * 16) ^ ((s & 7) << 4);
#pragma unroll
  for (int h = 0; h < Hc; h++) {
    *(uint4*)(kbuf + ((size_t)(b * Hc + h) * Sc + s) * 256 + off) = v;
  }
}

// ---------------- flash attention, 32x32 MFMA + swapped QK^T + in-register P (round-6, best) ----------------
__global__ __launch_bounds__(128, 2)
void attn_kernel(const ushort_t* __restrict__ qb, const char* __restrict__ kbuf,
                 const char* __restrict__ vtb, const ushort_t* __restrict__ m4,
                 ushort_t* __restrict__ attn_o)
{
  __shared__ __align__(16) char smem[32768];
  char* sK = smem;            // 16KB: 64 k-rows x 256B (swizzled)
  char* sV = smem + 16384;    // 16KB: 128 vd-rows x 128B (swizzled)
  const float scale2 = 0.12752081738040466f;  // 128^-0.5 / ln2
  int bid = blockIdx.x;
  bid = (bid & 7) * 128 + (bid >> 3);        // XCD-chunked swizzle (1024 % 8 == 0)
  int qt = bid & 31, bh = bid >> 5;
  int b = bh >> 4, h = bh & 15;
  int tid = threadIdx.x, wave = tid >> 6, lane = tid & 63;
  int l32 = lane & 31, half = lane >> 5;
  int sx = (l32 & 7) << 4;
  int qbase = qt * 64 + wave * 32;

  // Q fragments (B-operand): col = q = l32, k = ks*16 + half*8 + e
  bf16x8 qf[8];
  {
    const ushort_t* qp = qb + (size_t)(b * Sc + qbase + l32) * 2048 + h * 128 + half * 8;
#pragma unroll
    for (int ks = 0; ks < 8; ks++) qf[ks] = *(const bf16x8*)(qp + ks * 16);
  }

  float mrun = -3.0e38f, lrun = 0.f;   // per-lane scalars for q = qbase + l32
  f32x16 acco[4] = {};                  // [vdblk]; rows = q reg-pattern, col = vd

  const char* kg = kbuf + (size_t)bh * 524288;
  const char* vg = vtb + (size_t)bh * 524288;
  const ushort8v* mq = (const ushort8v*)m4 + (size_t)(qbase + l32) * 256 + half * 2;

  for (int kt = 0; kt < 32; kt++) {
    // stage K tile: 16KB linear (global bytes pre-swizzled)
#pragma unroll
    for (int it = 0; it < 8; it++)
      gload16(kg + kt * 16384 + it * 2048 + tid * 16, sK + it * 2048 + tid * 16);
    // stage V^T tile: 16KB, per-vd-row 128B chunks (global bytes pre-swizzled)
#pragma unroll
    for (int it = 0; it < 8; it++) {
      int l = it * 2048 + tid * 16;
      gload16(vg + (size_t)(l >> 7) * 4096 + kt * 128 + (l & 127), sV + l);
    }
    // mask fragments for this tile (4 x 16B, coalesced; latency hides under stage)
    ushort8v mvv[4];
#pragma unroll
    for (int kb = 0; kb < 2; kb++)
#pragma unroll
      for (int rr = 0; rr < 2; rr++)
        mvv[kb * 2 + rr] = mq[kt * 8 + kb * 4 + rr];
    __syncthreads();

#pragma unroll
    for (int kblk = 0; kblk < 2; kblk++) {
      // QK^T (swapped): sc rows = k (32), cols = q (32)
      f32x16 sc = {};
      __builtin_amdgcn_s_setprio(1);
#pragma unroll
      for (int ks = 0; ks < 8; ks++) {
        bf16x8 kfr = *(const bf16x8*)(sK + (kblk * 32 + l32) * 256 +
                                      ((ks * 32 + half * 16) ^ sx));
        sc = MFMA32(kfr, qf[ks], sc, 0, 0, 0);
      }
      __builtin_amdgcn_s_setprio(0);

      // lane-local softmax: lane holds P[q=l32][k = (r&3)+8*(r>>2)+4*half + kblk*32]
#pragma unroll
      for (int r = 0; r < 16; r++)
        sc[r] = sc[r] * scale2 + bf2f(mvv[kblk * 2 + (r >> 3)][r & 7]);
      float mx = sc[0];
#pragma unroll
      for (int r = 1; r < 16; r++) mx = fmaxf(mx, sc[r]);
      mx = fmaxf(mx, __shfl_xor(mx, 32));
      if (!__all(mx <= mrun + 11.0f)) {       // T13 defer-max (rare)
        float mnew = fmaxf(mrun, mx);
        float corr = __builtin_amdgcn_exp2f(mrun - mnew);
        lrun *= corr; mrun = mnew;
#pragma unroll
        for (int r = 0; r < 16; r++) {
          float cr = __shfl(corr, (r & 3) + 8 * (r >> 2) + 4 * half);
#pragma unroll
          for (int vb = 0; vb < 4; vb++) acco[vb][r] *= cr;
        }
      }
      float rs = 0.f;
      uint32_t W[8];
#pragma unroll
      for (int m = 0; m < 4; m++) {
        float p0 = __builtin_amdgcn_exp2f(sc[4 * m + 0] - mrun);
        float p1 = __builtin_amdgcn_exp2f(sc[4 * m + 1] - mrun);
        float p2 = __builtin_amdgcn_exp2f(sc[4 * m + 2] - mrun);
        float p3 = __builtin_amdgcn_exp2f(sc[4 * m + 3] - mrun);
        rs += (p0 + p1) + (p2 + p3);
        W[2 * m] = cvtpk(p0, p1);
        W[2 * m + 1] = cvtpk(p2, p3);
      }
      lrun += rs;   // lane-partial (this half's k); combined in epilogue

      // redistribute P to PV A-frag layout: frag[k2] k = k2*16 + half*8 + e
      bf16x8 pf[2];
#pragma unroll
      for (int k2 = 0; k2 < 2; k2++) {
        uint32_t a0 = W[4 * k2 + 0], a1 = W[4 * k2 + 1];
        uint32_t b0 = W[4 * k2 + 2], b1 = W[4 * k2 + 3];
        plswap(a0, b0);
        plswap(a1, b1);
        u32x4 t; t[0] = a0; t[1] = a1; t[2] = b0; t[3] = b1;
        pf[k2] = __builtin_bit_cast(bf16x8, t);
      }

      // PV: acco[vb] += P(32q x 32k) . V(32k x 128vd)
      __builtin_amdgcn_s_setprio(1);
#pragma unroll
      for (int k2 = 0; k2 < 2; k2++)
#pragma unroll
        for (int vb = 0; vb < 4; vb++) {
          bf16x8 vf = *(const bf16x8*)(sV + (vb * 32 + l32) * 128 +
                                       ((kblk * 64 + k2 * 32 + half * 16) ^ sx));
          acco[vb] = MFMA32(pf[k2], vf, acco[vb], 0, 0, 0);
        }
      __builtin_amdgcn_s_setprio(0);
    }

    __syncthreads();   // all waves done reading sK/sV before next stage
  }

  // epilogue: combine half-partial l, divide, store
  lrun += __shfl_xor(lrun, 32);
#pragma unroll
  for (int r = 0; r < 16; r++) {
    int rowq = (r & 3) + 8 * (r >> 2) + 4 * half;
    float lr = __shfl(lrun, rowq);
    float inv = 1.0f / lr;
    int qrow = qbase + rowq;
    ushort_t* op = attn_o + (size_t)(b * Sc + qrow) * 2048 + h * 128 + l32;
#pragma unroll
    for (int vb = 0; vb < 4; vb++)
      op[vb * 32] = f2bf(acco[vb][r] * inv);
  }
}

extern "C" void kernel_launch(void* const* d_in, const int* in_sizes, int n_in,
                              void* d_out, int out_size, void* d_ws, size_t ws_size,
                              hipStream_t stream) {
  const float* x    = (const float*)d_in[0];
  const float* mask = (const float*)d_in[1];
  const float* Wkvd = (const float*)d_in[2];
  const float* Wkvu = (const float*)d_in[3];
  const float* Wq   = (const float*)d_in[4];
  const float* Wout = (const float*)d_in[5];

  char* ws = (char*)d_ws;
  size_t off = 0;
  auto alloc = [&](size_t bytes) { char* p = ws + off; off += (bytes + 255) & ~(size_t)255; return p; };
  ushort_t* xb   = (ushort_t*)alloc((size_t)4096 * 2048 * 2);
  ushort_t* wkvd = (ushort_t*)alloc((size_t)640 * 2048 * 2);
  ushort_t* wq   = (ushort_t*)alloc((size_t)2048 * 2048 * 2);
  ushort_t* wkvu = (ushort_t*)alloc((size_t)3072 * 512 * 2);
  ushort_t* wout = (ushort_t*)alloc((size_t)2048 * 2048 * 2);
  ushort_t* comp = (ushort_t*)alloc((size_t)4096 * 640 * 2);
  ushort_t* qbuf = (ushort_t*)alloc((size_t)4096 * 2048 * 2);
  char*     kbuf = alloc((size_t)Bc * Hc * Sc * 256);
  char*     vtb  = alloc((size_t)Bc * Hc * 524288);
  ushort_t* attn_o = xb;   // xb dead after q-GEMM; reuse
  ushort_t* m4 = wq;       // wq dead after q-GEMM; reuse (8MB)

  // all casts in one launch
  cast_all<<<19200, 256, 0, stream>>>(x, Wq, Wkvu, Wout, Wkvd, xb, wq, wkvu, wout, wkvd);

  // compressed = x . W_kv_down^T  (N padded 576->640)
  gemm_bt<0><<<32 * 5, 256, 0, stream>>>(xb, 2048, wkvd, 2048, comp, 640, 4096, 640, 2048, nullptr, nullptr);
  // q = x . W_q^T
  gemm_bt<0><<<32 * 16, 256, 0, stream>>>(xb, 2048, wq, 2048, qbuf, 2048, 4096, 2048, 2048, nullptr, nullptr);
  // mask -> 32x32 swapped fragment order bf16 * (1/ln2)  (after q-GEMM: m4 overlays wq)
  mask_rearrange<<<2048, 256, 0, stream>>>(mask, m4);
  // kv_exp = kv_c . W_kv_up^T, scattered into vT(swizzled) + kbuf(nope, swizzled)
  gemm_bt<1><<<32 * 24, 256, 0, stream>>>(comp, 640, wkvu, 512, nullptr, 0, 4096, 3072, 512, vtb, kbuf);
  // k_rope broadcast into kbuf (swizzled)
  rope_fill<<<32768 / 256, 256, 0, stream>>>(comp, kbuf);
  // flash attention (round-6 structure: best measured, 113.5 us)
  attn_kernel<<<1024, 128, 0, stream>>>(qbuf, kbuf, vtb, m4, attn_o);
  // out = attn . W_out^T (fp32 store)
  gemm_bt<2><<<32 * 16, 256, 0, stream>>>(attn_o, 2048, wout, 2048, d_out, 2048, 4096, 2048, 2048, nullptr, nullptr);
}